// Round 9
// baseline (740.664 us; speedup 1.0000x reference)
//
#include <hip/hip_runtime.h>
#include <hip/hip_bf16.h>

typedef __bf16 bf16_t;
typedef bf16_t bf16x8 __attribute__((ext_vector_type(8)));
typedef float f32x4 __attribute__((ext_vector_type(4)));
typedef unsigned short ushort_t;

#define LD 104   // padded LDS row stride (bf16 elems) for GEMM staging tiles

__device__ __forceinline__ float bf2f(unsigned short u) {
    return __uint_as_float(((unsigned)u) << 16);
}
__device__ __forceinline__ unsigned short f2bfu(float x) {
    union { bf16_t b; unsigned short u; } c; c.b = (bf16_t)x; return c.u;
}
__device__ __forceinline__ unsigned pk2(float x, float y) {
    return (unsigned)f2bfu(x) | ((unsigned)f2bfu(y) << 16);
}

// load 6 consecutive bf16 (as 3 dwords) -> 6 floats
#define LD6(PTR, OUT) { \
    unsigned u0 = *(const unsigned*)(PTR); \
    unsigned u1 = *(const unsigned*)((PTR) + 2); \
    unsigned u2 = *(const unsigned*)((PTR) + 4); \
    OUT[0] = bf2f(u0 & 0xffff); OUT[1] = bf2f(u0 >> 16); \
    OUT[2] = bf2f(u1 & 0xffff); OUT[3] = bf2f(u1 >> 16); \
    OUT[4] = bf2f(u2 & 0xffff); OUT[5] = bf2f(u2 >> 16); }

// load 3 raw dwords (6 bf16) into U[3]
#define LD3U(PTR, U) { const unsigned* _p = (const unsigned*)(PTR); \
    U[0] = _p[0]; U[1] = _p[1]; U[2] = _p[2]; }
// unpack U[3] -> 6 floats
#define UNP6(U, OUT) { \
    OUT[0] = bf2f(U[0] & 0xffff); OUT[1] = bf2f(U[0] >> 16); \
    OUT[2] = bf2f(U[1] & 0xffff); OUT[3] = bf2f(U[1] >> 16); \
    OUT[4] = bf2f(U[2] & 0xffff); OUT[5] = bf2f(U[2] >> 16); }

// ---------------- weight convert: 5 x [96][96] f32 -> bf16 ----------------
__global__ void conv_w_kernel(const float* __restrict__ A, const float* __restrict__ B,
                              const float* __restrict__ C, const float* __restrict__ Dw,
                              const float* __restrict__ Ew, bf16_t* __restrict__ wb) {
    int i = blockIdx.x * 256 + threadIdx.x;
    if (i >= 5 * 9216) return;
    int m = i / 9216, j = i % 9216;
    const float* p = (m == 0) ? A : (m == 1) ? B : (m == 2) ? C : (m == 3) ? Dw : Ew;
    wb[i] = (bf16_t)p[j];
}

// ---------------- pack C_w into per-lane MFMA B-fragment order ----------------
// col remap: tile col c (=lane&15) of tile tn -> physical col c*6 + tn
__global__ void pack_cw_kernel(const float* __restrict__ Cw, bf16_t* __restrict__ wpack) {
    int idx = blockIdx.x * 256 + threadIdx.x;
    if (idx >= 18 * 64) return;
    int frag = idx >> 6, l = idx & 63;
    int tn = frag / 3, kk = frag % 3;
    int row = (l & 15) * 6 + tn;
    int c0 = kk * 32 + (l >> 4) * 8;
    bf16_t* o = wpack + (size_t)idx * 8;
#pragma unroll
    for (int j = 0; j < 8; ++j) o[j] = (bf16_t)Cw[row * 96 + c0 + j];
}

// ---------------- node GEMM ----------------
// mat 0 -> Ah (f32, nodeF_A[n][96]); mat 1,2,3 -> Bh,Dh,El(+Cb) bf16 into gpack[n][288]
__global__ __launch_bounds__(256) void node_gemm_kernel(
    const float* __restrict__ h, const bf16_t* __restrict__ wb,
    const float* __restrict__ Ab, const float* __restrict__ Bb,
    const float* __restrict__ Db, const float* __restrict__ Eb,
    const float* __restrict__ Cb,
    float* __restrict__ nodeF_A, ushort_t* __restrict__ gpack, int N)
{
    __shared__ __align__(16) bf16_t sx[64 * LD];
    __shared__ __align__(16) bf16_t sw[96 * LD];
    const int mat = blockIdx.y;
    const int widx = (mat < 2) ? mat : mat + 1;
    const float* bias = (mat == 0) ? Ab : (mat == 1) ? Bb : (mat == 2) ? Db : Eb;
    const int n0 = blockIdx.x * 64;
    const int t = threadIdx.x;

    for (int i = t; i < 64 * 96; i += 256) {
        int r = i / 96, c = i % 96;
        int n = n0 + r;
        float v = (n < N) ? h[n * 96 + c] : 0.f;
        sx[r * LD + c] = (bf16_t)v;
    }
    {
        const unsigned* W4 = (const unsigned*)(wb + widx * 9216);
        for (int i = t; i < 96 * 48; i += 256) {
            int r = i / 48, c = (i % 48) * 2;
            *(unsigned*)&sw[r * LD + c] = W4[i];
        }
    }
    __syncthreads();

    const int w = t >> 6, l = t & 63;
    const int lr = l & 15, lkb = (l >> 4) * 8;
    f32x4 acc[6];
#pragma unroll
    for (int i = 0; i < 6; ++i) acc[i] = (f32x4){0.f, 0.f, 0.f, 0.f};
    const bf16_t* aP = &sx[(w * 16 + lr) * LD + lkb];
#pragma unroll
    for (int kk = 0; kk < 3; ++kk) {
        bf16x8 a = *(const bf16x8*)(aP + kk * 32);
#pragma unroll
        for (int tn = 0; tn < 6; ++tn) {
            bf16x8 b = *(const bf16x8*)(&sw[(tn * 16 + lr) * LD + kk * 32 + lkb]);
            acc[tn] = __builtin_amdgcn_mfma_f32_16x16x32_bf16(a, b, acc[tn], 0, 0, 0);
        }
    }
    const int rowb = (l >> 4) * 4;
#pragma unroll
    for (int tn = 0; tn < 6; ++tn) {
        const int col = tn * 16 + lr;
        float bv = bias[col];
        if (mat == 3) bv += Cb[col];
#pragma unroll
        for (int i = 0; i < 4; ++i) {
            int n = n0 + w * 16 + rowb + i;
            if (n < N) {
                float v = acc[tn][i] + bv;
                if (mat == 0) nodeF_A[(size_t)n * 96 + col] = v;
                else gpack[(size_t)n * 288 + (mat - 1) * 96 + col] = f2bfu(v);
            }
        }
    }
}

// ---------------- Ce GEMM: en_s[inv[row]][96] = bf16(e[row] @ Cw^T) ----------------
// sequential e read; scatter WRITE into dst-sorted slot (writes don't stall).
__global__ __launch_bounds__(256) void ce_gemm_kernel(
    const float* __restrict__ eP, const bf16_t* __restrict__ wpack,
    const int* __restrict__ inv, ushort_t* __restrict__ en_s, int E)
{
    __shared__ __align__(16) bf16_t sx[64 * LD];
    const int n0 = blockIdx.x * 64;
    const int t = threadIdx.x;
    for (int i = t; i < 64 * 24; i += 256) {
        int r = i / 24, c4 = i % 24;
        int n = n0 + r;
        float4 v = (n < E) ? ((const float4*)eP)[(size_t)n * 24 + c4]
                           : make_float4(0.f, 0.f, 0.f, 0.f);
        bf16_t* p = &sx[r * LD + c4 * 4];
        p[0] = (bf16_t)v.x; p[1] = (bf16_t)v.y; p[2] = (bf16_t)v.z; p[3] = (bf16_t)v.w;
    }
    __syncthreads();

    const int w = t >> 6, l = t & 63;
    const int lr = l & 15, lkb = (l >> 4) * 8;
    f32x4 acc[6];
#pragma unroll
    for (int i = 0; i < 6; ++i) acc[i] = (f32x4){0.f, 0.f, 0.f, 0.f};
    const bf16_t* aP = &sx[(w * 16 + lr) * LD + lkb];
    const bf16x8* wp = (const bf16x8*)wpack;
#pragma unroll
    for (int kk = 0; kk < 3; ++kk) {
        bf16x8 a = *(const bf16x8*)(aP + kk * 32);
#pragma unroll
        for (int tn = 0; tn < 6; ++tn) {
            bf16x8 b = wp[(tn * 3 + kk) * 64 + l];
            acc[tn] = __builtin_amdgcn_mfma_f32_16x16x32_bf16(a, b, acc[tn], 0, 0, 0);
        }
    }
    const int rowb = (l >> 4) * 4;
#pragma unroll
    for (int i = 0; i < 4; ++i) {
        int n = n0 + w * 16 + rowb + i;
        if (n < E) {
            int g = inv[n];
            unsigned* op = (unsigned*)(en_s + (size_t)g * 96 + lr * 6);
            op[0] = pk2(acc[0][i], acc[1][i]);
            op[1] = pk2(acc[2][i], acc[3][i]);
            op[2] = pk2(acc[4][i], acc[5][i]);
        }
    }
}

// ---------------- counting sort by dst ----------------
__global__ void hist_kernel(const int* __restrict__ dst, int* __restrict__ cnt, int E) {
    int i = blockIdx.x * 256 + threadIdx.x;
    if (i < E) atomicAdd(&cnt[dst[i]], 1);
}

__global__ __launch_bounds__(1024) void scan_kernel(const int* __restrict__ cnt,
                                                    int* __restrict__ rowptr, int N) {
    __shared__ int wsum[16];
    __shared__ int s_carry;
    const int t = threadIdx.x;
    const int w = t >> 6, l = t & 63;
    if (t == 0) s_carry = 0;
    __syncthreads();
    for (int base = 0; base < N; base += 1024) {
        int v = (base + t < N) ? cnt[base + t] : 0;
        int x = v;
#pragma unroll
        for (int d = 1; d < 64; d <<= 1) {
            int y = __shfl_up(x, d, 64);
            if (l >= d) x += y;
        }
        if (l == 63) wsum[w] = x;
        __syncthreads();
        int carry = s_carry;
        int woff = 0;
        for (int i = 0; i < w; ++i) woff += wsum[i];
        int incl = carry + woff + x;
        if (base + t < N) rowptr[base + t] = incl - v;
        __syncthreads();
        if (t == 1023) s_carry = incl;
    }
}

// writes perm (sorted->orig), inv (orig->sorted), sorted srcs; cursor ends = inclusive rowptr
__global__ void scatter_kernel(const int* __restrict__ dst, const int* __restrict__ src,
                               int* __restrict__ cursor,
                               int* __restrict__ perm, int* __restrict__ inv,
                               int* __restrict__ srcs, int E) {
    int i = blockIdx.x * 256 + threadIdx.x;
    if (i < E) {
        int d = dst[i];
        int p = atomicAdd(&cursor[d], 1);
        perm[p] = i;
        inv[i] = p;
        srcs[p] = src[i];
    }
}

// ---------------- CSR node-parallel aggregation (no atomics to node data) ----------------
// 16-lane group per node; lane owns cols lr*6..lr*6+5.
// en_s (sorted): Ce. e_new = Ce + Dh[src] + (Eh[dst]+Cb) written to en_out at
// perm[g] (SCATTER_OUT=1: natural order, streaming edge_out) or g (in place).
// 2-stage software pipeline over the degree loop hides L3 gather latency.
// Also writes h_new = Ah + sh/(sg+eps); BN-h + BN-e stats.
template <int SCATTER_OUT>
__global__ __launch_bounds__(256, 4) void csr_agg_kernel(
    const int* __restrict__ rowend, const int* __restrict__ srcs,
    const int* __restrict__ perm,
    const ushort_t* __restrict__ gpack, const ushort_t* en_s, ushort_t* en_out,
    const float* __restrict__ nodeF_A, float* __restrict__ h_new,
    float* __restrict__ stats, int N)
{
    __shared__ float bns[96], bnq[96], bsh[96], bqh[96];
    const int t = threadIdx.x;
    if (t < 96) { bns[t] = 0.f; bnq[t] = 0.f; bsh[t] = 0.f; bqh[t] = 0.f; }
    __syncthreads();

    const int gi = t >> 4, lr = t & 15;
    const int n = blockIdx.x * 16 + gi;
    float ls[6] = {0, 0, 0, 0, 0, 0}, lq[6] = {0, 0, 0, 0, 0, 0};

    if (n < N) {
        const int beg = (n == 0) ? 0 : rowend[n - 1];
        const int end = rowend[n];
        float eh6[6];
        LD6(gpack + (size_t)n * 288 + 192 + lr * 6, eh6);
        float ash[6] = {0, 0, 0, 0, 0, 0}, asg[6] = {0, 0, 0, 0, 0, 0};

        unsigned cu[3] = {0, 0, 0}, bu[3] = {0, 0, 0}, du[3] = {0, 0, 0};
        int pcur = 0;
        if (beg < end) {
            int s = srcs[beg];
            pcur = SCATTER_OUT ? perm[beg] : beg;
            LD3U(en_s + (size_t)beg * 96 + lr * 6, cu);
            LD3U(gpack + (size_t)s * 288 + lr * 6, bu);
            LD3U(gpack + (size_t)s * 288 + 96 + lr * 6, du);
        }
        for (int g = beg; g < end; ++g) {
            unsigned cn[3] = {0, 0, 0}, bn2[3] = {0, 0, 0}, dn[3] = {0, 0, 0};
            int pnext = 0;
            if (g + 1 < end) {
                int s = srcs[g + 1];
                pnext = SCATTER_OUT ? perm[g + 1] : (g + 1);
                LD3U(en_s + (size_t)(g + 1) * 96 + lr * 6, cn);
                LD3U(gpack + (size_t)s * 288 + lr * 6, bn2);
                LD3U(gpack + (size_t)s * 288 + 96 + lr * 6, dn);
            }
            float ce6[6], bh6[6], dh6[6];
            UNP6(cu, ce6); UNP6(bu, bh6); UNP6(du, dh6);
            float en6[6];
#pragma unroll
            for (int k = 0; k < 6; ++k) {
                float en = ce6[k] + dh6[k] + eh6[k];
                float sg = 1.f / (1.f + __expf(-en));
                ash[k] += sg * bh6[k];
                asg[k] += sg;
                ls[k] += en; lq[k] += en * en;
                en6[k] = en;
            }
            unsigned* op = (unsigned*)(en_out + (size_t)pcur * 96 + lr * 6);
            op[0] = pk2(en6[0], en6[1]);
            op[1] = pk2(en6[2], en6[3]);
            op[2] = pk2(en6[4], en6[5]);
            cu[0] = cn[0]; cu[1] = cn[1]; cu[2] = cn[2];
            bu[0] = bn2[0]; bu[1] = bn2[1]; bu[2] = bn2[2];
            du[0] = dn[0]; du[1] = dn[1]; du[2] = dn[2];
            pcur = pnext;
        }

        const float* ap = nodeF_A + (size_t)n * 96 + lr * 6;
        float* hp = h_new + (size_t)n * 96 + lr * 6;
#pragma unroll
        for (int k = 0; k < 6; ++k) {
            float v = ap[k] + ash[k] / (asg[k] + 1e-6f);
            hp[k] = v;
            atomicAdd(&bsh[lr * 6 + k], v);
            atomicAdd(&bqh[lr * 6 + k], v * v);
        }
    }
#pragma unroll
    for (int k = 0; k < 6; ++k) {
        atomicAdd(&bns[lr * 6 + k], ls[k]);
        atomicAdd(&bnq[lr * 6 + k], lq[k]);
    }
    __syncthreads();
    if (t < 96) {
        unsafeAtomicAdd(&stats[t], bsh[t]);
        unsafeAtomicAdd(&stats[96 + t], bqh[t]);
        unsafeAtomicAdd(&stats[192 + t], bns[t]);
        unsafeAtomicAdd(&stats[288 + t], bnq[t]);
    }
}

// ---------------- streaming edge output (plan A): all-sequential ----------------
__global__ __launch_bounds__(256) void edge_out_fast_kernel(
    const float* __restrict__ eP, const ushort_t* __restrict__ en_nat,
    const float* __restrict__ coef, float* __restrict__ eout, long long total4)
{
    long long idx = (long long)blockIdx.x * 256 + threadIdx.x;
    if (idx >= total4) return;
    int c4 = (int)(idx % 24) * 4;
    float4 res = ((const float4*)eP)[idx];
    ushort4 nb = ((const ushort4*)en_nat)[idx];
    float4 o;
    o.x = res.x + fmaxf(0.f, bf2f(nb.x) * coef[192 + c4 + 0] + coef[288 + c4 + 0]);
    o.y = res.y + fmaxf(0.f, bf2f(nb.y) * coef[192 + c4 + 1] + coef[288 + c4 + 1]);
    o.z = res.z + fmaxf(0.f, bf2f(nb.z) * coef[192 + c4 + 2] + coef[288 + c4 + 2]);
    o.w = res.w + fmaxf(0.f, bf2f(nb.w) * coef[192 + c4 + 3] + coef[288 + c4 + 3]);
    ((float4*)eout)[idx] = o;
}

// ---------------- edge output (plan B): gather e_new from sorted slot via inv ----------------
__global__ __launch_bounds__(256) void edge_out_b_kernel(
    const float* __restrict__ eP, const ushort_t* __restrict__ en_s,
    const int* __restrict__ inv, const float* __restrict__ coef,
    float* __restrict__ eout, long long total4)
{
    long long idx = (long long)blockIdx.x * 256 + threadIdx.x;
    if (idx >= total4) return;
    int row = (int)(idx / 24);
    int c4 = (int)(idx % 24) * 4;
    float4 res = ((const float4*)eP)[idx];
    int g = inv[row];
    ushort4 nb = *(const ushort4*)(en_s + (size_t)g * 96 + c4);
    float4 o;
    o.x = res.x + fmaxf(0.f, bf2f(nb.x) * coef[192 + c4 + 0] + coef[288 + c4 + 0]);
    o.y = res.y + fmaxf(0.f, bf2f(nb.y) * coef[192 + c4 + 1] + coef[288 + c4 + 1]);
    o.z = res.z + fmaxf(0.f, bf2f(nb.z) * coef[192 + c4 + 2] + coef[288 + c4 + 2]);
    o.w = res.w + fmaxf(0.f, bf2f(nb.w) * coef[192 + c4 + 3] + coef[288 + c4 + 3]);
    ((float4*)eout)[idx] = o;
}

// ---------------- fallback edge aggregation (atomic path, small ws) ----------------
__global__ __launch_bounds__(256) void edge_agg_fb_kernel(
    const float* __restrict__ eP, const int* __restrict__ src, const int* __restrict__ dst,
    const int* __restrict__ perm, const bf16_t* __restrict__ wpack,
    const ushort_t* __restrict__ gpack,
    float* __restrict__ node_acc, float* __restrict__ stats, int E)
{
    __shared__ int seid[64], ssrcS[64], sdstS[64];
    __shared__ float bns[96], bnq[96];

    const int t = threadIdx.x;
    const int e0 = blockIdx.x * 64;

    if (t < 64) {
        int ge = e0 + t;
        int eid = (ge < E) ? perm[ge] : -1;
        seid[t] = eid;
        ssrcS[t] = (eid >= 0) ? src[eid] : 0;
        sdstS[t] = (eid >= 0) ? dst[eid] : -1;
    }
    if (t >= 64 && t < 160) { bns[t - 64] = 0.f; bnq[t - 64] = 0.f; }
    __syncthreads();

    const int w = t >> 6, l = t & 63;
    const int lr = l & 15, lkb = (l >> 4) * 8;

    int eida = seid[w * 16 + lr];
    if (eida < 0) eida = 0;
    const float* arow = eP + (size_t)eida * 96 + lkb;
    bf16x8 a[3];
#pragma unroll
    for (int kk = 0; kk < 3; ++kk) {
        float4 a0 = *(const float4*)(arow + kk * 32);
        float4 a1 = *(const float4*)(arow + kk * 32 + 4);
        a[kk][0] = (bf16_t)a0.x; a[kk][1] = (bf16_t)a0.y;
        a[kk][2] = (bf16_t)a0.z; a[kk][3] = (bf16_t)a0.w;
        a[kk][4] = (bf16_t)a1.x; a[kk][5] = (bf16_t)a1.y;
        a[kk][6] = (bf16_t)a1.z; a[kk][7] = (bf16_t)a1.w;
    }
    f32x4 acc[6];
#pragma unroll
    for (int i = 0; i < 6; ++i) acc[i] = (f32x4){0.f, 0.f, 0.f, 0.f};
    const bf16x8* wp = (const bf16x8*)wpack;
#pragma unroll
    for (int kk = 0; kk < 3; ++kk) {
#pragma unroll
        for (int tn = 0; tn < 6; ++tn) {
            bf16x8 b = wp[(tn * 3 + kk) * 64 + l];
            acc[tn] = __builtin_amdgcn_mfma_f32_16x16x32_bf16(a[kk], b, acc[tn], 0, 0, 0);
        }
    }

    const int rowb = (l >> 4) * 4;
    float ls[6] = {0, 0, 0, 0, 0, 0}, lq[6] = {0, 0, 0, 0, 0, 0};
#pragma unroll
    for (int i = 0; i < 4; ++i) {
        const int r = w * 16 + rowb + i;
        const int dd = sdstS[r], s = ssrcS[r];
        const bool ok = (dd >= 0);
        const int ddu = ok ? dd : 0;
        float bh6[6], dh6[6], eh6[6];
        LD6(gpack + (size_t)s * 288 + lr * 6, bh6);
        LD6(gpack + (size_t)s * 288 + 96 + lr * 6, dh6);
        LD6(gpack + (size_t)ddu * 288 + 192 + lr * 6, eh6);
#pragma unroll
        for (int tn = 0; tn < 6; ++tn) {
            float en = acc[tn][i] + dh6[tn] + eh6[tn];
            if (ok) {
                float sgv = 1.f / (1.f + __expf(-en));
                float shv = sgv * bh6[tn];
                ls[tn] += en; lq[tn] += en * en;
                unsafeAtomicAdd(node_acc + (size_t)dd * 192 + lr * 6 + tn, shv);
                unsafeAtomicAdd(node_acc + (size_t)dd * 192 + 96 + lr * 6 + tn, sgv);
            }
        }
    }

#pragma unroll
    for (int tn = 0; tn < 6; ++tn) {
        float s = ls[tn], q = lq[tn];
        s += __shfl_xor(s, 16, 64); q += __shfl_xor(q, 16, 64);
        s += __shfl_xor(s, 32, 64); q += __shfl_xor(q, 32, 64);
        if (l < 16) {
            atomicAdd(&bns[lr * 6 + tn], s);
            atomicAdd(&bnq[lr * 6 + tn], q);
        }
    }
    __syncthreads();
    if (t < 96) {
        unsafeAtomicAdd(&stats[192 + t], bns[t]);
        unsafeAtomicAdd(&stats[288 + t], bnq[t]);
    }
}

// ---------------- fallback h_new + BN-h stats ----------------
__global__ __launch_bounds__(192) void h_new_kernel(
    const float* __restrict__ nodeF_A, const float* __restrict__ node_acc,
    float* __restrict__ h_new, float* __restrict__ stats, int N)
{
    __shared__ float bs[192], bq[192];
    const int t = threadIdx.x;
    const int col = t % 96, half = t / 96;
    const int n0 = blockIdx.x * 32;
    float ls = 0.f, lq = 0.f;
    for (int r = half; r < 32; r += 2) {
        int n = n0 + r;
        if (n >= N) break;
        float ssum = node_acc[(size_t)n * 192 + 96 + col];
        float shh = node_acc[(size_t)n * 192 + col];
        float v = nodeF_A[(size_t)n * 96 + col] + shh / (ssum + 1e-6f);
        h_new[(size_t)n * 96 + col] = v;
        ls += v; lq += v * v;
    }
    bs[t] = ls; bq[t] = lq;
    __syncthreads();
    if (t < 96) {
        unsafeAtomicAdd(&stats[t], bs[t] + bs[t + 96]);
        unsafeAtomicAdd(&stats[96 + t], bq[t] + bq[t + 96]);
    }
}

// ---------------- fallback edge output (recompute path, gpack gathers) ----------------
__global__ __launch_bounds__(256) void edge_out_kernel(
    const float* __restrict__ eP, const int* __restrict__ src, const int* __restrict__ dst,
    const bf16_t* __restrict__ wpack, const ushort_t* __restrict__ gpack,
    const float* __restrict__ coef, float* __restrict__ eout, int E)
{
    const int t = threadIdx.x;
    const int e0 = blockIdx.x * 64;
    const int w = t >> 6, l = t & 63;
    const int lr = l & 15, lkb = (l >> 4) * 8;

    int eida = e0 + w * 16 + (l & 15);
    if (eida >= E) eida = E - 1;
    const float* arow = eP + (size_t)eida * 96 + lkb;
    bf16x8 a[3];
#pragma unroll
    for (int kk = 0; kk < 3; ++kk) {
        float4 a0 = *(const float4*)(arow + kk * 32);
        float4 a1 = *(const float4*)(arow + kk * 32 + 4);
        a[kk][0] = (bf16_t)a0.x; a[kk][1] = (bf16_t)a0.y;
        a[kk][2] = (bf16_t)a0.z; a[kk][3] = (bf16_t)a0.w;
        a[kk][4] = (bf16_t)a1.x; a[kk][5] = (bf16_t)a1.y;
        a[kk][6] = (bf16_t)a1.z; a[kk][7] = (bf16_t)a1.w;
    }
    f32x4 acc[6];
#pragma unroll
    for (int i = 0; i < 6; ++i) acc[i] = (f32x4){0.f, 0.f, 0.f, 0.f};
    const bf16x8* wp = (const bf16x8*)wpack;
#pragma unroll
    for (int kk = 0; kk < 3; ++kk) {
#pragma unroll
        for (int tn = 0; tn < 6; ++tn) {
            bf16x8 b = wp[(tn * 3 + kk) * 64 + l];
            acc[tn] = __builtin_amdgcn_mfma_f32_16x16x32_bf16(a[kk], b, acc[tn], 0, 0, 0);
        }
    }

    const int rowb = (l >> 4) * 4;
#pragma unroll
    for (int i = 0; i < 4; ++i) {
        const int r = w * 16 + rowb + i;
        const int ge = e0 + r;
        if (ge < E) {
            const int s = src[ge], dd = dst[ge];
            float dh6[6], eh6[6];
            LD6(gpack + (size_t)s * 288 + 96 + lr * 6, dh6);
            LD6(gpack + (size_t)dd * 288 + 192 + lr * 6, eh6);
#pragma unroll
            for (int tn = 0; tn < 6; ++tn) {
                const int col = lr * 6 + tn;
                float en = acc[tn][i] + dh6[tn] + eh6[tn];
                float res = eP[(size_t)ge * 96 + col];
                eout[(size_t)ge * 96 + col] =
                    res + fmaxf(0.f, en * coef[192 + col] + coef[288 + col]);
            }
        }
    }
}

// ---------------- stats -> scale/shift coefs ----------------
__global__ void finalize_stats_kernel(const float* __restrict__ stats, float* __restrict__ coef,
                                      const float* __restrict__ gh, const float* __restrict__ bh,
                                      const float* __restrict__ ge, const float* __restrict__ be,
                                      int N, int E)
{
    int t = threadIdx.x;
    if (t < 96) {
        float m = stats[t] / (float)N;
        float v = stats[96 + t] / (float)N - m * m;
        float rs = rsqrtf(v + 1e-5f);
        float sc = gh[t] * rs;
        coef[t] = sc;
        coef[96 + t] = bh[t] - m * sc;
    } else if (t < 192) {
        int c = t - 96;
        float m = stats[192 + c] / (float)E;
        float v = stats[288 + c] / (float)E - m * m;
        float rs = rsqrtf(v + 1e-5f);
        float sc = ge[c] * rs;
        coef[192 + c] = sc;
        coef[288 + c] = be[c] - m * sc;
    }
}

// ---------------- h output: h + relu(h_new*sc + sh) ----------------
__global__ __launch_bounds__(256) void h_out_kernel(
    const float* __restrict__ h, const float* __restrict__ h_new,
    const float* __restrict__ coef, float* __restrict__ out, int N)
{
    int idx = blockIdx.x * 256 + threadIdx.x;  // one float4
    int total = N * 24;
    if (idx >= total) return;
    int c4 = (idx % 24) * 4;
    float4 hv = ((const float4*)h)[idx];
    float4 nv = ((const float4*)h_new)[idx];
    float4 o;
    o.x = hv.x + fmaxf(0.f, nv.x * coef[c4 + 0] + coef[96 + c4 + 0]);
    o.y = hv.y + fmaxf(0.f, nv.y * coef[c4 + 1] + coef[96 + c4 + 1]);
    o.z = hv.z + fmaxf(0.f, nv.z * coef[c4 + 2] + coef[96 + c4 + 2]);
    o.w = hv.w + fmaxf(0.f, nv.w * coef[c4 + 3] + coef[96 + c4 + 3]);
    ((float4*)out)[idx] = o;
}

extern "C" void kernel_launch(void* const* d_in, const int* in_sizes, int n_in,
                              void* d_out, int out_size, void* d_ws, size_t ws_size,
                              hipStream_t stream)
{
    const float* h   = (const float*)d_in[0];
    const float* e   = (const float*)d_in[1];
    const int*   src = (const int*)d_in[2];
    const int*   dst = (const int*)d_in[3];
    const float* Aw  = (const float*)d_in[4];
    const float* Ab  = (const float*)d_in[5];
    const float* Bw  = (const float*)d_in[6];
    const float* Bb  = (const float*)d_in[7];
    const float* Cw  = (const float*)d_in[8];
    const float* Cb  = (const float*)d_in[9];
    const float* Dw  = (const float*)d_in[10];
    const float* Db  = (const float*)d_in[11];
    const float* Ewt = (const float*)d_in[12];
    const float* Eb  = (const float*)d_in[13];
    const float* gh  = (const float*)d_in[14];
    const float* bh  = (const float*)d_in[15];
    const float* ge  = (const float*)d_in[16];
    const float* be  = (const float*)d_in[17];

    const int N = in_sizes[0] / 96;
    const int E = in_sizes[2];

    float* ws        = (float*)d_ws;
    float* nodeF_A   = ws;                              // N*96 f32
    float* regR      = nodeF_A + (size_t)N * 96;        // N*192 f32 (idx arrays / fb node_acc)
    float* h_new     = regR + (size_t)N * 192;          // N*96 f32
    float* stats     = h_new + (size_t)N * 96;          // 384 f32
    float* coef      = stats + 384;                     // 384 f32
    bf16_t* wb       = (bf16_t*)(coef + 384);           // 5*9216 bf16
    bf16_t* wpack    = wb + 5 * 9216;                   // 1152*8 bf16 (packed C_w)
    ushort_t* gpack  = (ushort_t*)(wpack + 9216);       // N*288 bf16
    ushort_t* en_s   = gpack + (size_t)N * 288 + 16;    // E*96 bf16 (sorted Ce)
    ushort_t* en_nat = en_s + (size_t)E * 96;           // E*96 bf16 (natural e_new, plan A)

    const size_t need_B = (size_t)((char*)(en_s + (size_t)E * 96) - (char*)d_ws);
    const size_t need_A = (size_t)((char*)(en_nat + (size_t)E * 96) - (char*)d_ws);
    const bool idx_fit = ((size_t)(2 * N + 3 * E) * 4 <= (size_t)N * 192 * 4);
    const int plan = (ws_size >= need_A && idx_fit) ? 2
                   : (ws_size >= need_B && idx_fit) ? 1 : 0;
    const int nblk64 = (E + 63) / 64;

    if (plan >= 1) {
        // idx arrays live in regR (node_acc not needed on this path)
        int* cnt    = (int*)regR;
        int* rowptr = cnt + N;        // after scatter: inclusive row ends
        int* perm   = rowptr + N;
        int* srcs   = perm + E;
        int* inv    = srcs + E;

        hipMemsetAsync(cnt, 0, (size_t)N * sizeof(int), stream);
        hipMemsetAsync(stats, 0, 384 * sizeof(float), stream);
        conv_w_kernel<<<dim3(180), dim3(256), 0, stream>>>(Aw, Bw, Cw, Dw, Ewt, wb);
        pack_cw_kernel<<<dim3(5), dim3(256), 0, stream>>>(Cw, wpack);
        node_gemm_kernel<<<dim3((N + 63) / 64, 4), dim3(256), 0, stream>>>(
            h, wb, Ab, Bb, Db, Eb, Cb, nodeF_A, gpack, N);
        hist_kernel<<<dim3((E + 255) / 256), dim3(256), 0, stream>>>(dst, cnt, E);
        scan_kernel<<<dim3(1), dim3(1024), 0, stream>>>(cnt, rowptr, N);
        scatter_kernel<<<dim3((E + 255) / 256), dim3(256), 0, stream>>>(
            dst, src, rowptr, perm, inv, srcs, E);
        ce_gemm_kernel<<<dim3(nblk64), dim3(256), 0, stream>>>(e, wpack, inv, en_s, E);

        if (plan == 2) {
            csr_agg_kernel<1><<<dim3((N + 15) / 16), dim3(256), 0, stream>>>(
                rowptr, srcs, perm, gpack, en_s, en_nat, nodeF_A, h_new, stats, N);
        } else {
            csr_agg_kernel<0><<<dim3((N + 15) / 16), dim3(256), 0, stream>>>(
                rowptr, srcs, perm, gpack, en_s, en_s, nodeF_A, h_new, stats, N);
        }

        finalize_stats_kernel<<<dim3(1), dim3(192), 0, stream>>>(stats, coef, gh, bh, ge, be, N, E);
        h_out_kernel<<<dim3((N * 24 + 255) / 256), dim3(256), 0, stream>>>(
            h, h_new, coef, (float*)d_out, N);

        long long total4 = (long long)E * 24;
        float* eout = (float*)d_out + (size_t)N * 96;
        if (plan == 2) {
            edge_out_fast_kernel<<<dim3((unsigned)((total4 + 255) / 256)), dim3(256), 0, stream>>>(
                e, en_nat, coef, eout, total4);
        } else {
            edge_out_b_kernel<<<dim3((unsigned)((total4 + 255) / 256)), dim3(256), 0, stream>>>(
                e, en_s, inv, coef, eout, total4);
        }
    } else {
        // fallback: atomic aggregation, recompute edge output (no en buffers)
        float* node_acc = regR;
        int* perm = (int*)h_new;
        int* inv  = perm + E;
        int* srcs = inv + E;
        int* cnt    = (int*)node_acc;
        int* rowptr = cnt + N;

        hipMemsetAsync(cnt, 0, (size_t)N * sizeof(int), stream);
        conv_w_kernel<<<dim3(180), dim3(256), 0, stream>>>(Aw, Bw, Cw, Dw, Ewt, wb);
        pack_cw_kernel<<<dim3(5), dim3(256), 0, stream>>>(Cw, wpack);
        node_gemm_kernel<<<dim3((N + 63) / 64, 4), dim3(256), 0, stream>>>(
            h, wb, Ab, Bb, Db, Eb, Cb, nodeF_A, gpack, N);
        hist_kernel<<<dim3((E + 255) / 256), dim3(256), 0, stream>>>(dst, cnt, E);
        scan_kernel<<<dim3(1), dim3(1024), 0, stream>>>(cnt, rowptr, N);
        scatter_kernel<<<dim3((E + 255) / 256), dim3(256), 0, stream>>>(
            dst, src, rowptr, perm, inv, srcs, E);

        hipMemsetAsync(node_acc, 0, (size_t)N * 192 * sizeof(float), stream);
        hipMemsetAsync(stats, 0, 384 * sizeof(float), stream);

        edge_agg_fb_kernel<<<dim3(nblk64), dim3(256), 0, stream>>>(
            e, src, dst, perm, wpack, gpack, node_acc, stats, E);
        h_new_kernel<<<dim3((N + 31) / 32), dim3(192), 0, stream>>>(
            nodeF_A, node_acc, h_new, stats, N);
        finalize_stats_kernel<<<dim3(1), dim3(192), 0, stream>>>(stats, coef, gh, bh, ge, be, N, E);
        h_out_kernel<<<dim3((N * 24 + 255) / 256), dim3(256), 0, stream>>>(
            h, h_new, coef, (float*)d_out, N);
        edge_out_kernel<<<dim3(nblk64), dim3(256), 0, stream>>>(
            e, src, dst, wpack, gpack, coef, (float*)d_out + (size_t)N * 96, E);
    }
}

// Round 10
// 659.716 us; speedup vs baseline: 1.1227x; 1.1227x over previous
//
#include <hip/hip_runtime.h>
#include <hip/hip_bf16.h>

typedef __bf16 bf16_t;
typedef bf16_t bf16x8 __attribute__((ext_vector_type(8)));
typedef float f32x4 __attribute__((ext_vector_type(4)));
typedef unsigned short ushort_t;

#define LD 104   // padded LDS row stride (bf16 elems) for GEMM staging tiles

__device__ __forceinline__ float bf2f(unsigned short u) {
    return __uint_as_float(((unsigned)u) << 16);
}
__device__ __forceinline__ unsigned short f2bfu(float x) {
    union { bf16_t b; unsigned short u; } c; c.b = (bf16_t)x; return c.u;
}
__device__ __forceinline__ unsigned pk2(float x, float y) {
    return (unsigned)f2bfu(x) | ((unsigned)f2bfu(y) << 16);
}

// load 6 consecutive bf16 (as 3 dwords) -> 6 floats
#define LD6(PTR, OUT) { \
    unsigned u0 = *(const unsigned*)(PTR); \
    unsigned u1 = *(const unsigned*)((PTR) + 2); \
    unsigned u2 = *(const unsigned*)((PTR) + 4); \
    OUT[0] = bf2f(u0 & 0xffff); OUT[1] = bf2f(u0 >> 16); \
    OUT[2] = bf2f(u1 & 0xffff); OUT[3] = bf2f(u1 >> 16); \
    OUT[4] = bf2f(u2 & 0xffff); OUT[5] = bf2f(u2 >> 16); }

// load 3 raw dwords (6 bf16) into U[3]
#define LD3U(PTR, U) { const unsigned* _p = (const unsigned*)(PTR); \
    U[0] = _p[0]; U[1] = _p[1]; U[2] = _p[2]; }
// unpack U[3] -> 6 floats
#define UNP6(U, OUT) { \
    OUT[0] = bf2f(U[0] & 0xffff); OUT[1] = bf2f(U[0] >> 16); \
    OUT[2] = bf2f(U[1] & 0xffff); OUT[3] = bf2f(U[1] >> 16); \
    OUT[4] = bf2f(U[2] & 0xffff); OUT[5] = bf2f(U[2] >> 16); }

// ---------------- weight convert: 5 x [96][96] f32 -> bf16 ----------------
__global__ void conv_w_kernel(const float* __restrict__ A, const float* __restrict__ B,
                              const float* __restrict__ C, const float* __restrict__ Dw,
                              const float* __restrict__ Ew, bf16_t* __restrict__ wb) {
    int i = blockIdx.x * 256 + threadIdx.x;
    if (i >= 5 * 9216) return;
    int m = i / 9216, j = i % 9216;
    const float* p = (m == 0) ? A : (m == 1) ? B : (m == 2) ? C : (m == 3) ? Dw : Ew;
    wb[i] = (bf16_t)p[j];
}

// ---------------- pack C_w into per-lane MFMA B-fragment order ----------------
// col remap: tile col c (=lane&15) of tile tn -> physical col c*6 + tn
__global__ void pack_cw_kernel(const float* __restrict__ Cw, bf16_t* __restrict__ wpack) {
    int idx = blockIdx.x * 256 + threadIdx.x;
    if (idx >= 18 * 64) return;
    int frag = idx >> 6, l = idx & 63;
    int tn = frag / 3, kk = frag % 3;
    int row = (l & 15) * 6 + tn;
    int c0 = kk * 32 + (l >> 4) * 8;
    bf16_t* o = wpack + (size_t)idx * 8;
#pragma unroll
    for (int j = 0; j < 8; ++j) o[j] = (bf16_t)Cw[row * 96 + c0 + j];
}

// ---------------- node GEMM ----------------
// mat 0 -> Ah (f32, nodeF_A[n][96]); mat 1,2,3 -> Bh,Dh,El(+Cb) bf16 into gpack[n][288]
__global__ __launch_bounds__(256) void node_gemm_kernel(
    const float* __restrict__ h, const bf16_t* __restrict__ wb,
    const float* __restrict__ Ab, const float* __restrict__ Bb,
    const float* __restrict__ Db, const float* __restrict__ Eb,
    const float* __restrict__ Cb,
    float* __restrict__ nodeF_A, ushort_t* __restrict__ gpack, int N)
{
    __shared__ __align__(16) bf16_t sx[64 * LD];
    __shared__ __align__(16) bf16_t sw[96 * LD];
    const int mat = blockIdx.y;
    const int widx = (mat < 2) ? mat : mat + 1;
    const float* bias = (mat == 0) ? Ab : (mat == 1) ? Bb : (mat == 2) ? Db : Eb;
    const int n0 = blockIdx.x * 64;
    const int t = threadIdx.x;

    for (int i = t; i < 64 * 96; i += 256) {
        int r = i / 96, c = i % 96;
        int n = n0 + r;
        float v = (n < N) ? h[n * 96 + c] : 0.f;
        sx[r * LD + c] = (bf16_t)v;
    }
    {
        const unsigned* W4 = (const unsigned*)(wb + widx * 9216);
        for (int i = t; i < 96 * 48; i += 256) {
            int r = i / 48, c = (i % 48) * 2;
            *(unsigned*)&sw[r * LD + c] = W4[i];
        }
    }
    __syncthreads();

    const int w = t >> 6, l = t & 63;
    const int lr = l & 15, lkb = (l >> 4) * 8;
    f32x4 acc[6];
#pragma unroll
    for (int i = 0; i < 6; ++i) acc[i] = (f32x4){0.f, 0.f, 0.f, 0.f};
    const bf16_t* aP = &sx[(w * 16 + lr) * LD + lkb];
#pragma unroll
    for (int kk = 0; kk < 3; ++kk) {
        bf16x8 a = *(const bf16x8*)(aP + kk * 32);
#pragma unroll
        for (int tn = 0; tn < 6; ++tn) {
            bf16x8 b = *(const bf16x8*)(&sw[(tn * 16 + lr) * LD + kk * 32 + lkb]);
            acc[tn] = __builtin_amdgcn_mfma_f32_16x16x32_bf16(a, b, acc[tn], 0, 0, 0);
        }
    }
    const int rowb = (l >> 4) * 4;
#pragma unroll
    for (int tn = 0; tn < 6; ++tn) {
        const int col = tn * 16 + lr;
        float bv = bias[col];
        if (mat == 3) bv += Cb[col];
#pragma unroll
        for (int i = 0; i < 4; ++i) {
            int n = n0 + w * 16 + rowb + i;
            if (n < N) {
                float v = acc[tn][i] + bv;
                if (mat == 0) nodeF_A[(size_t)n * 96 + col] = v;
                else gpack[(size_t)n * 288 + (mat - 1) * 96 + col] = f2bfu(v);
            }
        }
    }
}

// ---------------- Ce GEMM: en_s[inv[row]][96] = bf16(e[row] @ Cw^T) ----------------
__global__ __launch_bounds__(256) void ce_gemm_kernel(
    const float* __restrict__ eP, const bf16_t* __restrict__ wpack,
    const int* __restrict__ inv, ushort_t* __restrict__ en_s, int E)
{
    __shared__ __align__(16) bf16_t sx[64 * LD];
    const int n0 = blockIdx.x * 64;
    const int t = threadIdx.x;
    for (int i = t; i < 64 * 24; i += 256) {
        int r = i / 24, c4 = i % 24;
        int n = n0 + r;
        float4 v = (n < E) ? ((const float4*)eP)[(size_t)n * 24 + c4]
                           : make_float4(0.f, 0.f, 0.f, 0.f);
        bf16_t* p = &sx[r * LD + c4 * 4];
        p[0] = (bf16_t)v.x; p[1] = (bf16_t)v.y; p[2] = (bf16_t)v.z; p[3] = (bf16_t)v.w;
    }
    __syncthreads();

    const int w = t >> 6, l = t & 63;
    const int lr = l & 15, lkb = (l >> 4) * 8;
    f32x4 acc[6];
#pragma unroll
    for (int i = 0; i < 6; ++i) acc[i] = (f32x4){0.f, 0.f, 0.f, 0.f};
    const bf16_t* aP = &sx[(w * 16 + lr) * LD + lkb];
    const bf16x8* wp = (const bf16x8*)wpack;
#pragma unroll
    for (int kk = 0; kk < 3; ++kk) {
        bf16x8 a = *(const bf16x8*)(aP + kk * 32);
#pragma unroll
        for (int tn = 0; tn < 6; ++tn) {
            bf16x8 b = wp[(tn * 3 + kk) * 64 + l];
            acc[tn] = __builtin_amdgcn_mfma_f32_16x16x32_bf16(a, b, acc[tn], 0, 0, 0);
        }
    }
    const int rowb = (l >> 4) * 4;
#pragma unroll
    for (int i = 0; i < 4; ++i) {
        int n = n0 + w * 16 + rowb + i;
        if (n < E) {
            int g = inv[n];
            unsigned* op = (unsigned*)(en_s + (size_t)g * 96 + lr * 6);
            op[0] = pk2(acc[0][i], acc[1][i]);
            op[1] = pk2(acc[2][i], acc[3][i]);
            op[2] = pk2(acc[4][i], acc[5][i]);
        }
    }
}

// ---------------- counting sort by dst ----------------
__global__ void hist_kernel(const int* __restrict__ dst, int* __restrict__ cnt, int E) {
    int i = blockIdx.x * 256 + threadIdx.x;
    if (i < E) atomicAdd(&cnt[dst[i]], 1);
}

// parallel unordered-base scan: each block scans its 1024-chunk locally and grabs
// a global base with ONE atomicAdd of its block sum. Ranges are contiguous per
// node but unordered across blocks -- fine for all consumers.
__global__ __launch_bounds__(1024) void scan_assign_kernel(
    const int* __restrict__ cnt, int* __restrict__ startA, int* __restrict__ cursor,
    int* __restrict__ gtot, int N)
{
    __shared__ int wsum[16];
    __shared__ int sbase;
    const int t = threadIdx.x, w = t >> 6, l = t & 63;
    const int base = blockIdx.x * 1024;
    int v = (base + t < N) ? cnt[base + t] : 0;
    int x = v;
#pragma unroll
    for (int d = 1; d < 64; d <<= 1) {
        int y = __shfl_up(x, d, 64);
        if (l >= d) x += y;
    }
    if (l == 63) wsum[w] = x;
    __syncthreads();
    if (t == 0) {
        int run = 0;
#pragma unroll
        for (int i = 0; i < 16; ++i) { int tmp = wsum[i]; wsum[i] = run; run += tmp; }
        sbase = atomicAdd(gtot, run);
    }
    __syncthreads();
    int excl = sbase + wsum[w] + (x - v);
    if (base + t < N) { startA[base + t] = excl; cursor[base + t] = excl; }
}

// writes inv (orig->slot), sorted srcs, optional perm; cursor ends at startA+cnt
__global__ void scatter_kernel(const int* __restrict__ dst, const int* __restrict__ src,
                               int* __restrict__ cursor, int* __restrict__ inv,
                               int* __restrict__ srcs, int* __restrict__ perm, int E) {
    int i = blockIdx.x * 256 + threadIdx.x;
    if (i < E) {
        int d = dst[i];
        int p = atomicAdd(&cursor[d], 1);
        inv[i] = p;
        srcs[p] = src[i];
        if (perm) perm[p] = i;
    }
}

// ---------------- CSR node-parallel aggregation ----------------
// 16-lane group per node; lane owns cols lr*6..lr*6+5.
// en_s (slot order): Ce in, e_new = Ce + Dh[src] + (Eh[dst]+Cb) out (in place).
// Degree loop unrolled x2 (both edges' gathers issue together, short live ranges).
// No trailing block barrier: last-wave-out flushes LDS stats (wave-level skew only).
__global__ __launch_bounds__(256, 4) void csr_agg_kernel(
    const int* __restrict__ startA, const int* __restrict__ rowend,
    const int* __restrict__ srcs,
    const ushort_t* __restrict__ gpack, ushort_t* __restrict__ en_s,
    const float* __restrict__ nodeF_A, float* __restrict__ h_new,
    float* __restrict__ stats, int N)
{
    __shared__ float bns[96], bnq[96], bsh[96], bqh[96];
    __shared__ int scnt;
    const int t = threadIdx.x;
    if (t == 0) scnt = 0;
    if (t < 96) { bns[t] = 0.f; bnq[t] = 0.f; bsh[t] = 0.f; bqh[t] = 0.f; }
    __syncthreads();

    const int gi = t >> 4, lr = t & 15, l = t & 63;
    const int n = blockIdx.x * 16 + gi;
    float ls[6] = {0, 0, 0, 0, 0, 0}, lq[6] = {0, 0, 0, 0, 0, 0};

    if (n < N) {
        const int beg = startA[n];
        const int end = rowend[n];
        float eh6[6];
        LD6(gpack + (size_t)n * 288 + 192 + lr * 6, eh6);
        float ash[6] = {0, 0, 0, 0, 0, 0}, asg[6] = {0, 0, 0, 0, 0, 0};

        int g = beg;
        for (; g + 2 <= end; g += 2) {
            int s0 = srcs[g], s1 = srcs[g + 1];
            unsigned c0[3], b0[3], d0[3], c1[3], b1[3], d1[3];
            LD3U(en_s + (size_t)g * 96 + lr * 6, c0);
            LD3U(en_s + (size_t)(g + 1) * 96 + lr * 6, c1);
            LD3U(gpack + (size_t)s0 * 288 + lr * 6, b0);
            LD3U(gpack + (size_t)s1 * 288 + lr * 6, b1);
            LD3U(gpack + (size_t)s0 * 288 + 96 + lr * 6, d0);
            LD3U(gpack + (size_t)s1 * 288 + 96 + lr * 6, d1);
            float ce6[6], bh6[6], dh6[6], en6[6];
            UNP6(c0, ce6); UNP6(b0, bh6); UNP6(d0, dh6);
#pragma unroll
            for (int k = 0; k < 6; ++k) {
                float en = ce6[k] + dh6[k] + eh6[k];
                float sg = 1.f / (1.f + __expf(-en));
                ash[k] += sg * bh6[k]; asg[k] += sg;
                ls[k] += en; lq[k] += en * en;
                en6[k] = en;
            }
            unsigned* op0 = (unsigned*)(en_s + (size_t)g * 96 + lr * 6);
            op0[0] = pk2(en6[0], en6[1]); op0[1] = pk2(en6[2], en6[3]); op0[2] = pk2(en6[4], en6[5]);
            UNP6(c1, ce6); UNP6(b1, bh6); UNP6(d1, dh6);
#pragma unroll
            for (int k = 0; k < 6; ++k) {
                float en = ce6[k] + dh6[k] + eh6[k];
                float sg = 1.f / (1.f + __expf(-en));
                ash[k] += sg * bh6[k]; asg[k] += sg;
                ls[k] += en; lq[k] += en * en;
                en6[k] = en;
            }
            unsigned* op1 = (unsigned*)(en_s + (size_t)(g + 1) * 96 + lr * 6);
            op1[0] = pk2(en6[0], en6[1]); op1[1] = pk2(en6[2], en6[3]); op1[2] = pk2(en6[4], en6[5]);
        }
        if (g < end) {
            int s0 = srcs[g];
            float ce6[6], bh6[6], dh6[6], en6[6];
            LD6(en_s + (size_t)g * 96 + lr * 6, ce6);
            LD6(gpack + (size_t)s0 * 288 + lr * 6, bh6);
            LD6(gpack + (size_t)s0 * 288 + 96 + lr * 6, dh6);
#pragma unroll
            for (int k = 0; k < 6; ++k) {
                float en = ce6[k] + dh6[k] + eh6[k];
                float sg = 1.f / (1.f + __expf(-en));
                ash[k] += sg * bh6[k]; asg[k] += sg;
                ls[k] += en; lq[k] += en * en;
                en6[k] = en;
            }
            unsigned* op = (unsigned*)(en_s + (size_t)g * 96 + lr * 6);
            op[0] = pk2(en6[0], en6[1]); op[1] = pk2(en6[2], en6[3]); op[2] = pk2(en6[4], en6[5]);
        }

        const float* ap = nodeF_A + (size_t)n * 96 + lr * 6;
        float* hp = h_new + (size_t)n * 96 + lr * 6;
#pragma unroll
        for (int k = 0; k < 6; ++k) {
            float v = ap[k] + ash[k] / (asg[k] + 1e-6f);
            hp[k] = v;
            atomicAdd(&bsh[lr * 6 + k], v);
            atomicAdd(&bqh[lr * 6 + k], v * v);
        }
    }
    // e-stat fold across the 4 groups in this wave (lanes sharing lr)
#pragma unroll
    for (int k = 0; k < 6; ++k) {
        float s = ls[k], q = lq[k];
        s += __shfl_xor(s, 16, 64); q += __shfl_xor(q, 16, 64);
        s += __shfl_xor(s, 32, 64); q += __shfl_xor(q, 32, 64);
        if (l < 16) {
            atomicAdd(&bns[lr * 6 + k], s);
            atomicAdd(&bnq[lr * 6 + k], q);
        }
    }
    // last-wave-out flush (no block barrier -> wave-level skew only)
    __threadfence_block();
    int old = 0;
    if (l == 0) old = atomicAdd(&scnt, 1);
    old = __shfl(old, 0, 64);
    if (old == 3) {
        for (int j = l; j < 96; j += 64) {
            unsafeAtomicAdd(&stats[j], bsh[j]);
            unsafeAtomicAdd(&stats[96 + j], bqh[j]);
            unsafeAtomicAdd(&stats[192 + j], bns[j]);
            unsafeAtomicAdd(&stats[288 + j], bnq[j]);
        }
    }
}

// ---------------- edge output: natural order, gather e_new via inv ----------------
__global__ __launch_bounds__(256) void edge_out_b_kernel(
    const float* __restrict__ eP, const ushort_t* __restrict__ en_s,
    const int* __restrict__ inv, const float* __restrict__ coef,
    float* __restrict__ eout, long long total4)
{
    long long idx = (long long)blockIdx.x * 256 + threadIdx.x;
    if (idx >= total4) return;
    int row = (int)(idx / 24);
    int c4 = (int)(idx % 24) * 4;
    float4 res = ((const float4*)eP)[idx];
    int g = inv[row];
    ushort4 nb = *(const ushort4*)(en_s + (size_t)g * 96 + c4);
    float4 o;
    o.x = res.x + fmaxf(0.f, bf2f(nb.x) * coef[192 + c4 + 0] + coef[288 + c4 + 0]);
    o.y = res.y + fmaxf(0.f, bf2f(nb.y) * coef[192 + c4 + 1] + coef[288 + c4 + 1]);
    o.z = res.z + fmaxf(0.f, bf2f(nb.z) * coef[192 + c4 + 2] + coef[288 + c4 + 2]);
    o.w = res.w + fmaxf(0.f, bf2f(nb.w) * coef[192 + c4 + 3] + coef[288 + c4 + 3]);
    ((float4*)eout)[idx] = o;
}

// ---------------- fallback edge aggregation (atomic path, small ws) ----------------
__global__ __launch_bounds__(256) void edge_agg_fb_kernel(
    const float* __restrict__ eP, const int* __restrict__ src, const int* __restrict__ dst,
    const int* __restrict__ perm, const bf16_t* __restrict__ wpack,
    const ushort_t* __restrict__ gpack,
    float* __restrict__ node_acc, float* __restrict__ stats, int E)
{
    __shared__ int seid[64], ssrcS[64], sdstS[64];
    __shared__ float bns[96], bnq[96];

    const int t = threadIdx.x;
    const int e0 = blockIdx.x * 64;

    if (t < 64) {
        int ge = e0 + t;
        int eid = (ge < E) ? perm[ge] : -1;
        seid[t] = eid;
        ssrcS[t] = (eid >= 0) ? src[eid] : 0;
        sdstS[t] = (eid >= 0) ? dst[eid] : -1;
    }
    if (t >= 64 && t < 160) { bns[t - 64] = 0.f; bnq[t - 64] = 0.f; }
    __syncthreads();

    const int w = t >> 6, l = t & 63;
    const int lr = l & 15, lkb = (l >> 4) * 8;

    int eida = seid[w * 16 + lr];
    if (eida < 0) eida = 0;
    const float* arow = eP + (size_t)eida * 96 + lkb;
    bf16x8 a[3];
#pragma unroll
    for (int kk = 0; kk < 3; ++kk) {
        float4 a0 = *(const float4*)(arow + kk * 32);
        float4 a1 = *(const float4*)(arow + kk * 32 + 4);
        a[kk][0] = (bf16_t)a0.x; a[kk][1] = (bf16_t)a0.y;
        a[kk][2] = (bf16_t)a0.z; a[kk][3] = (bf16_t)a0.w;
        a[kk][4] = (bf16_t)a1.x; a[kk][5] = (bf16_t)a1.y;
        a[kk][6] = (bf16_t)a1.z; a[kk][7] = (bf16_t)a1.w;
    }
    f32x4 acc[6];
#pragma unroll
    for (int i = 0; i < 6; ++i) acc[i] = (f32x4){0.f, 0.f, 0.f, 0.f};
    const bf16x8* wp = (const bf16x8*)wpack;
#pragma unroll
    for (int kk = 0; kk < 3; ++kk) {
#pragma unroll
        for (int tn = 0; tn < 6; ++tn) {
            bf16x8 b = wp[(tn * 3 + kk) * 64 + l];
            acc[tn] = __builtin_amdgcn_mfma_f32_16x16x32_bf16(a[kk], b, acc[tn], 0, 0, 0);
        }
    }

    const int rowb = (l >> 4) * 4;
    float ls[6] = {0, 0, 0, 0, 0, 0}, lq[6] = {0, 0, 0, 0, 0, 0};
#pragma unroll
    for (int i = 0; i < 4; ++i) {
        const int r = w * 16 + rowb + i;
        const int dd = sdstS[r], s = ssrcS[r];
        const bool ok = (dd >= 0);
        const int ddu = ok ? dd : 0;
        float bh6[6], dh6[6], eh6[6];
        LD6(gpack + (size_t)s * 288 + lr * 6, bh6);
        LD6(gpack + (size_t)s * 288 + 96 + lr * 6, dh6);
        LD6(gpack + (size_t)ddu * 288 + 192 + lr * 6, eh6);
#pragma unroll
        for (int tn = 0; tn < 6; ++tn) {
            float en = acc[tn][i] + dh6[tn] + eh6[tn];
            if (ok) {
                float sgv = 1.f / (1.f + __expf(-en));
                float shv = sgv * bh6[tn];
                ls[tn] += en; lq[tn] += en * en;
                unsafeAtomicAdd(node_acc + (size_t)dd * 192 + lr * 6 + tn, shv);
                unsafeAtomicAdd(node_acc + (size_t)dd * 192 + 96 + lr * 6 + tn, sgv);
            }
        }
    }

#pragma unroll
    for (int tn = 0; tn < 6; ++tn) {
        float s = ls[tn], q = lq[tn];
        s += __shfl_xor(s, 16, 64); q += __shfl_xor(q, 16, 64);
        s += __shfl_xor(s, 32, 64); q += __shfl_xor(q, 32, 64);
        if (l < 16) {
            atomicAdd(&bns[lr * 6 + tn], s);
            atomicAdd(&bnq[lr * 6 + tn], q);
        }
    }
    __syncthreads();
    if (t < 96) {
        unsafeAtomicAdd(&stats[192 + t], bns[t]);
        unsafeAtomicAdd(&stats[288 + t], bnq[t]);
    }
}

// ---------------- fallback h_new + BN-h stats ----------------
__global__ __launch_bounds__(192) void h_new_kernel(
    const float* __restrict__ nodeF_A, const float* __restrict__ node_acc,
    float* __restrict__ h_new, float* __restrict__ stats, int N)
{
    __shared__ float bs[192], bq[192];
    const int t = threadIdx.x;
    const int col = t % 96, half = t / 96;
    const int n0 = blockIdx.x * 32;
    float ls = 0.f, lq = 0.f;
    for (int r = half; r < 32; r += 2) {
        int n = n0 + r;
        if (n >= N) break;
        float ssum = node_acc[(size_t)n * 192 + 96 + col];
        float shh = node_acc[(size_t)n * 192 + col];
        float v = nodeF_A[(size_t)n * 96 + col] + shh / (ssum + 1e-6f);
        h_new[(size_t)n * 96 + col] = v;
        ls += v; lq += v * v;
    }
    bs[t] = ls; bq[t] = lq;
    __syncthreads();
    if (t < 96) {
        unsafeAtomicAdd(&stats[t], bs[t] + bs[t + 96]);
        unsafeAtomicAdd(&stats[96 + t], bq[t] + bq[t + 96]);
    }
}

// ---------------- fallback edge output (recompute path, gpack gathers) ----------------
__global__ __launch_bounds__(256) void edge_out_kernel(
    const float* __restrict__ eP, const int* __restrict__ src, const int* __restrict__ dst,
    const bf16_t* __restrict__ wpack, const ushort_t* __restrict__ gpack,
    const float* __restrict__ coef, float* __restrict__ eout, int E)
{
    const int t = threadIdx.x;
    const int e0 = blockIdx.x * 64;
    const int w = t >> 6, l = t & 63;
    const int lr = l & 15, lkb = (l >> 4) * 8;

    int eida = e0 + w * 16 + (l & 15);
    if (eida >= E) eida = E - 1;
    const float* arow = eP + (size_t)eida * 96 + lkb;
    bf16x8 a[3];
#pragma unroll
    for (int kk = 0; kk < 3; ++kk) {
        float4 a0 = *(const float4*)(arow + kk * 32);
        float4 a1 = *(const float4*)(arow + kk * 32 + 4);
        a[kk][0] = (bf16_t)a0.x; a[kk][1] = (bf16_t)a0.y;
        a[kk][2] = (bf16_t)a0.z; a[kk][3] = (bf16_t)a0.w;
        a[kk][4] = (bf16_t)a1.x; a[kk][5] = (bf16_t)a1.y;
        a[kk][6] = (bf16_t)a1.z; a[kk][7] = (bf16_t)a1.w;
    }
    f32x4 acc[6];
#pragma unroll
    for (int i = 0; i < 6; ++i) acc[i] = (f32x4){0.f, 0.f, 0.f, 0.f};
    const bf16x8* wp = (const bf16x8*)wpack;
#pragma unroll
    for (int kk = 0; kk < 3; ++kk) {
#pragma unroll
        for (int tn = 0; tn < 6; ++tn) {
            bf16x8 b = wp[(tn * 3 + kk) * 64 + l];
            acc[tn] = __builtin_amdgcn_mfma_f32_16x16x32_bf16(a[kk], b, acc[tn], 0, 0, 0);
        }
    }

    const int rowb = (l >> 4) * 4;
#pragma unroll
    for (int i = 0; i < 4; ++i) {
        const int r = w * 16 + rowb + i;
        const int ge = e0 + r;
        if (ge < E) {
            const int s = src[ge], dd = dst[ge];
            float dh6[6], eh6[6];
            LD6(gpack + (size_t)s * 288 + 96 + lr * 6, dh6);
            LD6(gpack + (size_t)dd * 288 + 192 + lr * 6, eh6);
#pragma unroll
            for (int tn = 0; tn < 6; ++tn) {
                const int col = lr * 6 + tn;
                float en = acc[tn][i] + dh6[tn] + eh6[tn];
                float res = eP[(size_t)ge * 96 + col];
                eout[(size_t)ge * 96 + col] =
                    res + fmaxf(0.f, en * coef[192 + col] + coef[288 + col]);
            }
        }
    }
}

// ---------------- stats -> scale/shift coefs ----------------
__global__ void finalize_stats_kernel(const float* __restrict__ stats, float* __restrict__ coef,
                                      const float* __restrict__ gh, const float* __restrict__ bh,
                                      const float* __restrict__ ge, const float* __restrict__ be,
                                      int N, int E)
{
    int t = threadIdx.x;
    if (t < 96) {
        float m = stats[t] / (float)N;
        float v = stats[96 + t] / (float)N - m * m;
        float rs = rsqrtf(v + 1e-5f);
        float sc = gh[t] * rs;
        coef[t] = sc;
        coef[96 + t] = bh[t] - m * sc;
    } else if (t < 192) {
        int c = t - 96;
        float m = stats[192 + c] / (float)E;
        float v = stats[288 + c] / (float)E - m * m;
        float rs = rsqrtf(v + 1e-5f);
        float sc = ge[c] * rs;
        coef[192 + c] = sc;
        coef[288 + c] = be[c] - m * sc;
    }
}

// ---------------- h output: h + relu(h_new*sc + sh) ----------------
__global__ __launch_bounds__(256) void h_out_kernel(
    const float* __restrict__ h, const float* __restrict__ h_new,
    const float* __restrict__ coef, float* __restrict__ out, int N)
{
    int idx = blockIdx.x * 256 + threadIdx.x;  // one float4
    int total = N * 24;
    if (idx >= total) return;
    int c4 = (idx % 24) * 4;
    float4 hv = ((const float4*)h)[idx];
    float4 nv = ((const float4*)h_new)[idx];
    float4 o;
    o.x = hv.x + fmaxf(0.f, nv.x * coef[c4 + 0] + coef[96 + c4 + 0]);
    o.y = hv.y + fmaxf(0.f, nv.y * coef[c4 + 1] + coef[96 + c4 + 1]);
    o.z = hv.z + fmaxf(0.f, nv.z * coef[c4 + 2] + coef[96 + c4 + 2]);
    o.w = hv.w + fmaxf(0.f, nv.w * coef[c4 + 3] + coef[96 + c4 + 3]);
    ((float4*)out)[idx] = o;
}

extern "C" void kernel_launch(void* const* d_in, const int* in_sizes, int n_in,
                              void* d_out, int out_size, void* d_ws, size_t ws_size,
                              hipStream_t stream)
{
    const float* h   = (const float*)d_in[0];
    const float* e   = (const float*)d_in[1];
    const int*   src = (const int*)d_in[2];
    const int*   dst = (const int*)d_in[3];
    const float* Aw  = (const float*)d_in[4];
    const float* Ab  = (const float*)d_in[5];
    const float* Bw  = (const float*)d_in[6];
    const float* Bb  = (const float*)d_in[7];
    const float* Cw  = (const float*)d_in[8];
    const float* Cb  = (const float*)d_in[9];
    const float* Dw  = (const float*)d_in[10];
    const float* Db  = (const float*)d_in[11];
    const float* Ewt = (const float*)d_in[12];
    const float* Eb  = (const float*)d_in[13];
    const float* gh  = (const float*)d_in[14];
    const float* bh  = (const float*)d_in[15];
    const float* ge  = (const float*)d_in[16];
    const float* be  = (const float*)d_in[17];

    const int N = in_sizes[0] / 96;
    const int E = in_sizes[2];

    float* ws        = (float*)d_ws;
    float* nodeF_A   = ws;                              // N*96 f32
    float* regR      = nodeF_A + (size_t)N * 96;        // N*192 f32 (idx arrays / fb node_acc)
    float* h_new     = regR + (size_t)N * 192;          // N*96 f32
    float* stats     = h_new + (size_t)N * 96;          // 384 f32
    float* coef      = stats + 384;                     // 384 f32
    bf16_t* wb       = (bf16_t*)(coef + 384);           // 5*9216 bf16
    bf16_t* wpack    = wb + 5 * 9216;                   // 1152*8 bf16 (packed C_w)
    ushort_t* gpack  = (ushort_t*)(wpack + 9216);       // N*288 bf16
    ushort_t* en_s   = gpack + (size_t)N * 288 + 16;    // E*96 bf16 (slot-order Ce -> e_new)

    const size_t need_main = (size_t)((char*)(en_s + (size_t)E * 96) - (char*)d_ws);
    const bool idx_fit = ((size_t)(3 * N + 2 * E + 1) * 4 <= (size_t)N * 192 * 4);
    const int plan = (ws_size >= need_main && idx_fit) ? 1 : 0;
    const int nblk64 = (E + 63) / 64;
    const int nscan = (N + 1023) / 1024;

    if (plan == 1) {
        int* cnt    = (int*)regR;
        int* startA = cnt + N;
        int* cursor = startA + N;     // after scatter: row ends
        int* srcs   = cursor + N;
        int* inv    = srcs + E;
        int* gtot   = inv + E;

        hipMemsetAsync(cnt, 0, (size_t)N * sizeof(int), stream);
        hipMemsetAsync(gtot, 0, sizeof(int), stream);
        hipMemsetAsync(stats, 0, 384 * sizeof(float), stream);
        conv_w_kernel<<<dim3(180), dim3(256), 0, stream>>>(Aw, Bw, Cw, Dw, Ewt, wb);
        pack_cw_kernel<<<dim3(5), dim3(256), 0, stream>>>(Cw, wpack);
        node_gemm_kernel<<<dim3((N + 63) / 64, 4), dim3(256), 0, stream>>>(
            h, wb, Ab, Bb, Db, Eb, Cb, nodeF_A, gpack, N);
        hist_kernel<<<dim3((E + 255) / 256), dim3(256), 0, stream>>>(dst, cnt, E);
        scan_assign_kernel<<<dim3(nscan), dim3(1024), 0, stream>>>(cnt, startA, cursor, gtot, N);
        scatter_kernel<<<dim3((E + 255) / 256), dim3(256), 0, stream>>>(
            dst, src, cursor, inv, srcs, nullptr, E);
        ce_gemm_kernel<<<dim3(nblk64), dim3(256), 0, stream>>>(e, wpack, inv, en_s, E);

        csr_agg_kernel<<<dim3((N + 15) / 16), dim3(256), 0, stream>>>(
            startA, cursor, srcs, gpack, en_s, nodeF_A, h_new, stats, N);

        finalize_stats_kernel<<<dim3(1), dim3(192), 0, stream>>>(stats, coef, gh, bh, ge, be, N, E);
        h_out_kernel<<<dim3((N * 24 + 255) / 256), dim3(256), 0, stream>>>(
            h, h_new, coef, (float*)d_out, N);

        long long total4 = (long long)E * 24;
        edge_out_b_kernel<<<dim3((unsigned)((total4 + 255) / 256)), dim3(256), 0, stream>>>(
            e, en_s, inv, coef, (float*)d_out + (size_t)N * 96, total4);
    } else {
        // fallback: atomic aggregation, recompute edge output (no en buffer)
        float* node_acc = regR;
        int* perm = (int*)h_new;
        int* inv  = perm + E;
        int* srcs = inv + E;
        int* gtot = srcs + E;
        int* cnt    = (int*)node_acc;
        int* startA = cnt + N;
        int* cursor = startA + N;

        hipMemsetAsync(cnt, 0, (size_t)N * sizeof(int), stream);
        hipMemsetAsync(gtot, 0, sizeof(int), stream);
        conv_w_kernel<<<dim3(180), dim3(256), 0, stream>>>(Aw, Bw, Cw, Dw, Ewt, wb);
        pack_cw_kernel<<<dim3(5), dim3(256), 0, stream>>>(Cw, wpack);
        node_gemm_kernel<<<dim3((N + 63) / 64, 4), dim3(256), 0, stream>>>(
            h, wb, Ab, Bb, Db, Eb, Cb, nodeF_A, gpack, N);
        hist_kernel<<<dim3((E + 255) / 256), dim3(256), 0, stream>>>(dst, cnt, E);
        scan_assign_kernel<<<dim3(nscan), dim3(1024), 0, stream>>>(cnt, startA, cursor, gtot, N);
        scatter_kernel<<<dim3((E + 255) / 256), dim3(256), 0, stream>>>(
            dst, src, cursor, inv, srcs, perm, E);

        hipMemsetAsync(node_acc, 0, (size_t)N * 192 * sizeof(float), stream);
        hipMemsetAsync(stats, 0, 384 * sizeof(float), stream);

        edge_agg_fb_kernel<<<dim3(nblk64), dim3(256), 0, stream>>>(
            e, src, dst, perm, wpack, gpack, node_acc, stats, E);
        h_new_kernel<<<dim3((N + 31) / 32), dim3(192), 0, stream>>>(
            nodeF_A, node_acc, h_new, stats, N);
        finalize_stats_kernel<<<dim3(1), dim3(192), 0, stream>>>(stats, coef, gh, bh, ge, be, N, E);
        h_out_kernel<<<dim3((N * 24 + 255) / 256), dim3(256), 0, stream>>>(
            h, h_new, coef, (float*)d_out, N);
        edge_out_kernel<<<dim3(nblk64), dim3(256), 0, stream>>>(
            e, src, dst, wpack, gpack, coef, (float*)d_out + (size_t)N * 96, E);
    }
}